// Round 1
// baseline (885.335 us; speedup 1.0000x reference)
//
#include <hip/hip_runtime.h>
#include <cstdint>
#include <cstddef>

static constexpr int HID = 128;
static constexpr int TASKS = 12;

// ---------------- index dtype detection + conversion ----------------
// If edge_index is int64 (little-endian, values < 2^31), every odd 32-bit
// word of the first 1024 elements is 0. If int32, those words are random
// node indices -> OR is nonzero with overwhelming probability.
__global__ void detect_i64(const unsigned int* __restrict__ ebuf, int* __restrict__ flag) {
    __shared__ unsigned int sh[256];
    const int t = threadIdx.x;
    unsigned int v = 0;
    for (int i = t; i < 1024; i += 256) v |= ebuf[2 * i + 1];
    sh[t] = v;
    __syncthreads();
    for (int s = 128; s > 0; s >>= 1) {
        if (t < s) sh[t] |= sh[t + s];
        __syncthreads();
    }
    if (t == 0) flag[0] = (sh[0] == 0u) ? 1 : 0;
}

__global__ void convert_edges(const void* __restrict__ ebuf, const int* __restrict__ flag,
                              int* __restrict__ src32, int* __restrict__ dst32,
                              int* __restrict__ deg, int E) {
    const int i = blockIdx.x * blockDim.x + threadIdx.x;
    if (i >= E) return;
    int s, d;
    if (*flag) {
        s = (int)((const long long*)ebuf)[i];
        d = (int)((const long long*)ebuf)[(size_t)E + i];
    } else {
        s = ((const int*)ebuf)[i];
        d = ((const int*)ebuf)[(size_t)E + i];
    }
    src32[i] = s;
    dst32[i] = d;
    atomicAdd(&deg[d], 1);
}

__global__ void convert_batch(const void* __restrict__ bbuf, const int* __restrict__ flag,
                              int* __restrict__ b32, int N) {
    const int i = blockIdx.x * blockDim.x + threadIdx.x;
    if (i >= N) return;
    b32[i] = (*flag) ? (int)((const long long*)bbuf)[i] : ((const int*)bbuf)[i];
}

// ---------------- exclusive scan (rowptr) ----------------
__global__ __launch_bounds__(256) void scan1(const int* __restrict__ deg, int* __restrict__ incl,
                                             int* __restrict__ bsums, int N) {
    __shared__ int sh[256];
    const int t = threadIdx.x;
    const int base = blockIdx.x * 1024 + t * 4;
    int v0 = (base + 0 < N) ? deg[base + 0] : 0;
    int v1 = (base + 1 < N) ? deg[base + 1] : 0;
    int v2 = (base + 2 < N) ? deg[base + 2] : 0;
    int v3 = (base + 3 < N) ? deg[base + 3] : 0;
    const int ts = v0 + v1 + v2 + v3;
    sh[t] = ts;
    __syncthreads();
    for (int off = 1; off < 256; off <<= 1) {
        int x = (t >= off) ? sh[t - off] : 0;
        __syncthreads();
        sh[t] += x;
        __syncthreads();
    }
    const int ex = sh[t] - ts;
    const int r0 = ex + v0, r1 = r0 + v1, r2 = r1 + v2, r3 = r2 + v3;
    if (base + 0 < N) incl[base + 0] = r0;
    if (base + 1 < N) incl[base + 1] = r1;
    if (base + 2 < N) incl[base + 2] = r2;
    if (base + 3 < N) incl[base + 3] = r3;
    if (t == 255) bsums[blockIdx.x] = sh[255];
}

__global__ __launch_bounds__(256) void scan2(int* __restrict__ bsums, int nb) {
    __shared__ int sh[256];
    const int t = threadIdx.x;
    const int v = (t < nb) ? bsums[t] : 0;
    sh[t] = v;
    __syncthreads();
    for (int off = 1; off < 256; off <<= 1) {
        int x = (t >= off) ? sh[t - off] : 0;
        __syncthreads();
        sh[t] += x;
        __syncthreads();
    }
    if (t < nb) bsums[t] = sh[t] - v;  // exclusive
}

__global__ __launch_bounds__(256) void scan3(const int* __restrict__ incl, const int* __restrict__ bsums,
                                             int* __restrict__ rowptr, int N) {
    const int t = threadIdx.x;
    const int base = blockIdx.x * 1024 + t * 4;
    const int off = bsums[blockIdx.x];
#pragma unroll
    for (int j = 0; j < 4; ++j) {
        if (base + j < N) rowptr[base + j + 1] = incl[base + j] + off;
    }
    if (blockIdx.x == 0 && t == 0) rowptr[0] = 0;
}

__global__ void scatter_edges(const int* __restrict__ src32, const int* __restrict__ dst32,
                              const int* __restrict__ rowptr, int* __restrict__ fill,
                              int* __restrict__ csr, int E) {
    const int i = blockIdx.x * blockDim.x + threadIdx.x;
    if (i >= E) return;
    const int d = dst32[i];
    const int pos = rowptr[d] + atomicAdd(&fill[d], 1);
    csr[pos] = src32[i];
}

// ---------------- mean aggregation: one wave per node ----------------
template <int D>
__global__ __launch_bounds__(256) void agg_kernel(const float* __restrict__ H,
                                                  const int* __restrict__ rowptr,
                                                  const int* __restrict__ csr,
                                                  float* __restrict__ AGG, int N) {
    const int gid = blockIdx.x * blockDim.x + threadIdx.x;
    const int node = gid >> 6;
    const int lane = gid & 63;
    if (node >= N) return;
    const int beg = rowptr[node];
    const int end = rowptr[node + 1];
    const float inv = 1.0f / fmaxf((float)(end - beg), 1.0f);
    if (D == 64) {
        float acc = 0.f;
        for (int k = beg; k < end; ++k) {
            const int s = csr[k];
            acc += H[(size_t)s * 64 + lane];
        }
        AGG[(size_t)node * 64 + lane] = acc * inv;
    } else {
        float ax = 0.f, ay = 0.f;
        for (int k = beg; k < end; ++k) {
            const int s = csr[k];
            const float2 v = *reinterpret_cast<const float2*>(H + (size_t)s * 128 + lane * 2);
            ax += v.x;
            ay += v.y;
        }
        *reinterpret_cast<float2*>(AGG + (size_t)node * 128 + lane * 2) = make_float2(ax * inv, ay * inv);
    }
}

// ---------------- fused SAGE linear: OUT = relu([X|AGG] @ [Wl|Wr]^T + b) ----------------
template <int DIN>
__global__ __launch_bounds__(256) void sage_gemm(const float* __restrict__ X,
                                                 const float* __restrict__ AGG,
                                                 const float* __restrict__ Wl,
                                                 const float* __restrict__ bl,
                                                 const float* __restrict__ Wr,
                                                 float* __restrict__ OUT, int N) {
    constexpr int BM = 64, BN = 128, BK = 32;
    constexpr int K2 = 2 * DIN;
    __shared__ float Xs[BK][BM + 4];
    __shared__ float Ws[BK][BN + 4];
    const int tid = threadIdx.x;
    const int tn = tid & 15;
    const int tm = tid >> 4;
    const int m0 = blockIdx.x * BM;

    const int ln = tid >> 2;           // node within tile (0..63)
    const int lk = (tid & 3) * 8;      // k offset within chunk
    const int wrow = tid >> 1;         // W row (0..127)
    const int wk = (tid & 1) * 16;     // k offset within chunk

    float acc[4][8];
#pragma unroll
    for (int i = 0; i < 4; ++i)
#pragma unroll
        for (int j = 0; j < 8; ++j) acc[i][j] = 0.f;

    for (int k0 = 0; k0 < K2; k0 += BK) {
        const bool first = (k0 < DIN);
        const float* __restrict__ xsrc = first ? X : AGG;
        const float* __restrict__ wsrc = first ? Wl : Wr;
        const int kcol = first ? k0 : (k0 - DIN);

        {  // stage X chunk, transposed
            const int node = m0 + ln;
            float4 a0 = {0, 0, 0, 0}, a1 = {0, 0, 0, 0};
            if (node < N) {
                const float4* p = reinterpret_cast<const float4*>(xsrc + (size_t)node * DIN + kcol + lk);
                a0 = p[0];
                a1 = p[1];
            }
            Xs[lk + 0][ln] = a0.x; Xs[lk + 1][ln] = a0.y; Xs[lk + 2][ln] = a0.z; Xs[lk + 3][ln] = a0.w;
            Xs[lk + 4][ln] = a1.x; Xs[lk + 5][ln] = a1.y; Xs[lk + 6][ln] = a1.z; Xs[lk + 7][ln] = a1.w;
        }
        {  // stage W chunk, transposed
            const float4* p = reinterpret_cast<const float4*>(wsrc + (size_t)wrow * DIN + kcol + wk);
            const float4 w0 = p[0], w1 = p[1], w2 = p[2], w3 = p[3];
            Ws[wk + 0][wrow] = w0.x;  Ws[wk + 1][wrow] = w0.y;  Ws[wk + 2][wrow] = w0.z;  Ws[wk + 3][wrow] = w0.w;
            Ws[wk + 4][wrow] = w1.x;  Ws[wk + 5][wrow] = w1.y;  Ws[wk + 6][wrow] = w1.z;  Ws[wk + 7][wrow] = w1.w;
            Ws[wk + 8][wrow] = w2.x;  Ws[wk + 9][wrow] = w2.y;  Ws[wk + 10][wrow] = w2.z; Ws[wk + 11][wrow] = w2.w;
            Ws[wk + 12][wrow] = w3.x; Ws[wk + 13][wrow] = w3.y; Ws[wk + 14][wrow] = w3.z; Ws[wk + 15][wrow] = w3.w;
        }
        __syncthreads();
#pragma unroll
        for (int kk = 0; kk < BK; ++kk) {
            const float4 xv = *reinterpret_cast<const float4*>(&Xs[kk][tm * 4]);
            const float4 wv0 = *reinterpret_cast<const float4*>(&Ws[kk][tn * 8]);
            const float4 wv1 = *reinterpret_cast<const float4*>(&Ws[kk][tn * 8 + 4]);
            const float xr[4] = {xv.x, xv.y, xv.z, xv.w};
            const float wr8[8] = {wv0.x, wv0.y, wv0.z, wv0.w, wv1.x, wv1.y, wv1.z, wv1.w};
#pragma unroll
            for (int i = 0; i < 4; ++i)
#pragma unroll
                for (int j = 0; j < 8; ++j) acc[i][j] = fmaf(xr[i], wr8[j], acc[i][j]);
        }
        __syncthreads();
    }

    const float4 bb0 = *reinterpret_cast<const float4*>(bl + tn * 8);
    const float4 bb1 = *reinterpret_cast<const float4*>(bl + tn * 8 + 4);
    const float bbr[8] = {bb0.x, bb0.y, bb0.z, bb0.w, bb1.x, bb1.y, bb1.z, bb1.w};
#pragma unroll
    for (int i = 0; i < 4; ++i) {
        const int node = m0 + tm * 4 + i;
        if (node < N) {
            float4 o0, o1;
            o0.x = fmaxf(acc[i][0] + bbr[0], 0.f);
            o0.y = fmaxf(acc[i][1] + bbr[1], 0.f);
            o0.z = fmaxf(acc[i][2] + bbr[2], 0.f);
            o0.w = fmaxf(acc[i][3] + bbr[3], 0.f);
            o1.x = fmaxf(acc[i][4] + bbr[4], 0.f);
            o1.y = fmaxf(acc[i][5] + bbr[5], 0.f);
            o1.z = fmaxf(acc[i][6] + bbr[6], 0.f);
            o1.w = fmaxf(acc[i][7] + bbr[7], 0.f);
            float* dst = OUT + (size_t)node * HID + tn * 8;
            *reinterpret_cast<float4*>(dst) = o0;
            *reinterpret_cast<float4*>(dst + 4) = o1;
        }
    }
}

// ---------------- global mean pool + output head ----------------
__global__ __launch_bounds__(128) void pool_kernel(const float* __restrict__ H,
                                                   const int* __restrict__ batch,
                                                   const float* __restrict__ Wout,
                                                   const float* __restrict__ bout,
                                                   float* __restrict__ out, int N, int G) {
    const int g = blockIdx.x;
    const int t = threadIdx.x;
    int lo = 0, hi = N;
    while (lo < hi) {
        const int mid = (lo + hi) >> 1;
        if (batch[mid] < g) lo = mid + 1; else hi = mid;
    }
    const int start = lo;
    hi = N;
    while (lo < hi) {
        const int mid = (lo + hi) >> 1;
        if (batch[mid] < g + 1) lo = mid + 1; else hi = mid;
    }
    const int end = lo;
    float acc = 0.f;
    for (int n = start; n < end; ++n) acc += H[(size_t)n * HID + t];
    const float inv = 1.0f / fmaxf((float)(end - start), 1.0f);
    __shared__ float pl[HID];
    pl[t] = acc * inv;
    __syncthreads();
    if (t < TASKS) {
        float dot = bout[t];
        const float* w = Wout + t * HID;
        for (int k = 0; k < HID; ++k) dot = fmaf(pl[k], w[k], dot);
        out[(size_t)g * TASKS + t] = dot;
    }
}

// ---------------- launcher ----------------
extern "C" void kernel_launch(void* const* d_in, const int* in_sizes, int n_in,
                              void* d_out, int out_size, void* d_ws, size_t ws_size,
                              hipStream_t stream) {
    const float* x    = (const float*)d_in[0];
    const void*  e    = d_in[1];
    const void*  bt   = d_in[2];
    const float* Wl1  = (const float*)d_in[3];
    const float* bl1  = (const float*)d_in[4];
    const float* Wr1  = (const float*)d_in[5];
    const float* Wl2  = (const float*)d_in[6];
    const float* bl2  = (const float*)d_in[7];
    const float* Wr2  = (const float*)d_in[8];
    const float* Wl3  = (const float*)d_in[9];
    const float* bl3  = (const float*)d_in[10];
    const float* Wr3  = (const float*)d_in[11];
    const float* Wout = (const float*)d_in[12];
    const float* bout = (const float*)d_in[13];
    float* out = (float*)d_out;

    const int N = in_sizes[0] / 64;
    const int E = in_sizes[1] / 2;
    const int G = out_size / TASKS;

    char* base = (char*)d_ws;
    size_t off = 0;
    auto alloc = [&](size_t bytes) -> void* {
        void* p = base + off;
        off += (bytes + 255) & ~(size_t)255;
        return p;
    };
    int* flag    = (int*)alloc(256);
    int* src32   = (int*)alloc((size_t)E * 4);
    int* dst32   = (int*)alloc((size_t)E * 4);
    int* b32     = (int*)alloc((size_t)N * 4);
    int* deg     = (int*)alloc((size_t)N * 4);
    int* incl    = (int*)alloc((size_t)N * 4);
    int* bsums   = (int*)alloc(1024 * 4);
    int* rowptr  = (int*)alloc(((size_t)N + 1) * 4);
    int* fill    = (int*)alloc((size_t)N * 4);
    int* csr     = (int*)alloc((size_t)E * 4);
    float* bufA  = (float*)alloc((size_t)N * HID * 4);
    float* bufB  = (float*)alloc((size_t)N * HID * 4);
    float* bufC  = (float*)alloc((size_t)N * HID * 4);
    (void)ws_size;
    (void)n_in;

    hipMemsetAsync(deg, 0, (size_t)N * 4, stream);
    hipMemsetAsync(fill, 0, (size_t)N * 4, stream);

    detect_i64<<<1, 256, 0, stream>>>((const unsigned int*)e, flag);
    convert_edges<<<(E + 255) / 256, 256, 0, stream>>>(e, flag, src32, dst32, deg, E);
    convert_batch<<<(N + 255) / 256, 256, 0, stream>>>(bt, flag, b32, N);

    const int nsb = (N + 1023) / 1024;
    scan1<<<nsb, 256, 0, stream>>>(deg, incl, bsums, N);
    scan2<<<1, 256, 0, stream>>>(bsums, nsb);
    scan3<<<nsb, 256, 0, stream>>>(incl, bsums, rowptr, N);
    scatter_edges<<<(E + 255) / 256, 256, 0, stream>>>(src32, dst32, rowptr, fill, csr, E);

    const int aggBlocks = (int)(((size_t)N * 64 + 255) / 256);
    const int gemmBlocks = (N + 63) / 64;

    agg_kernel<64><<<aggBlocks, 256, 0, stream>>>(x, rowptr, csr, bufA, N);
    sage_gemm<64><<<gemmBlocks, 256, 0, stream>>>(x, bufA, Wl1, bl1, Wr1, bufB, N);
    agg_kernel<128><<<aggBlocks, 256, 0, stream>>>(bufB, rowptr, csr, bufA, N);
    sage_gemm<128><<<gemmBlocks, 256, 0, stream>>>(bufB, bufA, Wl2, bl2, Wr2, bufC, N);
    agg_kernel<128><<<aggBlocks, 256, 0, stream>>>(bufC, rowptr, csr, bufB, N);
    sage_gemm<128><<<gemmBlocks, 256, 0, stream>>>(bufC, bufB, Wl3, bl3, Wr3, bufA, N);

    pool_kernel<<<G, 128, 0, stream>>>(bufA, b32, Wout, bout, out, N, G);
}

// Round 2
// 746.372 us; speedup vs baseline: 1.1862x; 1.1862x over previous
//
#include <hip/hip_runtime.h>
#include <cstdint>
#include <cstddef>

static constexpr int HID = 128;
static constexpr int TASKS = 12;

using short8 = __attribute__((ext_vector_type(8))) short;  // 8 bf16 (4 VGPRs)
using f32x4  = __attribute__((ext_vector_type(4))) float;  // MFMA accumulator

__device__ inline unsigned short f2bf(float f) {
    union { float f; unsigned u; } v{f};
    unsigned r = v.u + 0x7fff + ((v.u >> 16) & 1);  // RNE
    return (unsigned short)(r >> 16);
}
__device__ inline float bf2f(unsigned short b) {
    union { unsigned u; float f; } v{(unsigned)b << 16};
    return v.f;
}

// ---------------- index dtype detection + conversion ----------------
__global__ void detect_i64(const unsigned int* __restrict__ ebuf, int* __restrict__ flag) {
    __shared__ unsigned int sh[256];
    const int t = threadIdx.x;
    unsigned int v = 0;
    for (int i = t; i < 1024; i += 256) v |= ebuf[2 * i + 1];
    sh[t] = v;
    __syncthreads();
    for (int s = 128; s > 0; s >>= 1) {
        if (t < s) sh[t] |= sh[t + s];
        __syncthreads();
    }
    if (t == 0) flag[0] = (sh[0] == 0u) ? 1 : 0;
}

__global__ void convert_edges(const void* __restrict__ ebuf, const int* __restrict__ flag,
                              int* __restrict__ src32, int* __restrict__ dst32,
                              int* __restrict__ deg, int E) {
    const int i = blockIdx.x * blockDim.x + threadIdx.x;
    if (i >= E) return;
    int s, d;
    if (*flag) {
        s = (int)((const long long*)ebuf)[i];
        d = (int)((const long long*)ebuf)[(size_t)E + i];
    } else {
        s = ((const int*)ebuf)[i];
        d = ((const int*)ebuf)[(size_t)E + i];
    }
    src32[i] = s;
    dst32[i] = d;
    atomicAdd(&deg[d], 1);
}

__global__ void convert_batch(const void* __restrict__ bbuf, const int* __restrict__ flag,
                              int* __restrict__ b32, int N) {
    const int i = blockIdx.x * blockDim.x + threadIdx.x;
    if (i >= N) return;
    b32[i] = (*flag) ? (int)((const long long*)bbuf)[i] : ((const int*)bbuf)[i];
}

// ---------------- exclusive scan (rowptr) ----------------
__global__ __launch_bounds__(256) void scan1(const int* __restrict__ deg, int* __restrict__ incl,
                                             int* __restrict__ bsums, int N) {
    __shared__ int sh[256];
    const int t = threadIdx.x;
    const int base = blockIdx.x * 1024 + t * 4;
    int v0 = (base + 0 < N) ? deg[base + 0] : 0;
    int v1 = (base + 1 < N) ? deg[base + 1] : 0;
    int v2 = (base + 2 < N) ? deg[base + 2] : 0;
    int v3 = (base + 3 < N) ? deg[base + 3] : 0;
    const int ts = v0 + v1 + v2 + v3;
    sh[t] = ts;
    __syncthreads();
    for (int off = 1; off < 256; off <<= 1) {
        int x = (t >= off) ? sh[t - off] : 0;
        __syncthreads();
        sh[t] += x;
        __syncthreads();
    }
    const int ex = sh[t] - ts;
    const int r0 = ex + v0, r1 = r0 + v1, r2 = r1 + v2, r3 = r2 + v3;
    if (base + 0 < N) incl[base + 0] = r0;
    if (base + 1 < N) incl[base + 1] = r1;
    if (base + 2 < N) incl[base + 2] = r2;
    if (base + 3 < N) incl[base + 3] = r3;
    if (t == 255) bsums[blockIdx.x] = sh[255];
}

__global__ __launch_bounds__(256) void scan2(int* __restrict__ bsums, int nb) {
    __shared__ int sh[256];
    const int t = threadIdx.x;
    const int v = (t < nb) ? bsums[t] : 0;
    sh[t] = v;
    __syncthreads();
    for (int off = 1; off < 256; off <<= 1) {
        int x = (t >= off) ? sh[t - off] : 0;
        __syncthreads();
        sh[t] += x;
        __syncthreads();
    }
    if (t < nb) bsums[t] = sh[t] - v;  // exclusive
}

__global__ __launch_bounds__(256) void scan3(const int* __restrict__ incl, const int* __restrict__ bsums,
                                             int* __restrict__ rowptr, int N) {
    const int t = threadIdx.x;
    const int base = blockIdx.x * 1024 + t * 4;
    const int off = bsums[blockIdx.x];
#pragma unroll
    for (int j = 0; j < 4; ++j) {
        if (base + j < N) rowptr[base + j + 1] = incl[base + j] + off;
    }
    if (blockIdx.x == 0 && t == 0) rowptr[0] = 0;
}

__global__ void scatter_edges(const int* __restrict__ src32, const int* __restrict__ dst32,
                              const int* __restrict__ rowptr, int* __restrict__ fill,
                              int* __restrict__ csr, int E) {
    const int i = blockIdx.x * blockDim.x + threadIdx.x;
    if (i >= E) return;
    const int d = dst32[i];
    const int pos = rowptr[d] + atomicAdd(&fill[d], 1);
    csr[pos] = src32[i];
}

// ---------------- dtype conversions ----------------
// x f32 [N][64] -> buf1 bf16 [N][128] cols 0..63
__global__ void cvt_x(const float* __restrict__ x, unsigned short* __restrict__ buf1, int N) {
    const int idx = blockIdx.x * blockDim.x + threadIdx.x;  // N*16 threads, 4 elems each
    if (idx >= N * 16) return;
    const int n = idx >> 4;
    const int k4 = (idx & 15) * 4;
    const float4 v = *reinterpret_cast<const float4*>(x + (size_t)n * 64 + k4);
    ushort4 o;
    o.x = f2bf(v.x); o.y = f2bf(v.y); o.z = f2bf(v.z); o.w = f2bf(v.w);
    *reinterpret_cast<ushort4*>(buf1 + (size_t)n * 128 + k4) = o;
}

// W_l [128][KH], W_r [128][KH] f32 -> Wcat bf16 [128][2*KH]
__global__ void cvt_w(const float* __restrict__ Wl, const float* __restrict__ Wr,
                      unsigned short* __restrict__ out, int KH) {
    const int idx = blockIdx.x * blockDim.x + threadIdx.x;
    const int K2 = 2 * KH;
    if (idx >= 128 * K2) return;
    const int j = idx / K2;
    const int k = idx % K2;
    const float v = (k < KH) ? Wl[(size_t)j * KH + k] : Wr[(size_t)j * KH + k - KH];
    out[idx] = f2bf(v);
}

// ---------------- mean aggregation (bf16): one wave per node ----------------
template <int D>
__global__ __launch_bounds__(256) void agg_bf16(const unsigned short* __restrict__ src,
                                                unsigned short* __restrict__ dst, int stride,
                                                const int* __restrict__ rowptr,
                                                const int* __restrict__ csr, int N) {
    const int gid = blockIdx.x * blockDim.x + threadIdx.x;
    const int node = gid >> 6;
    const int lane = gid & 63;
    if (node >= N) return;
    const int beg = rowptr[node];
    const int end = rowptr[node + 1];
    const float inv = 1.0f / fmaxf((float)(end - beg), 1.0f);
    if (D == 64) {
        float acc = 0.f;
        for (int k = beg; k < end; ++k) {
            const int s = csr[k];
            acc += bf2f(src[(size_t)s * stride + lane]);
        }
        dst[(size_t)node * stride + lane] = f2bf(acc * inv);
    } else {
        float ax = 0.f, ay = 0.f;
        for (int k = beg; k < end; ++k) {
            const int s = csr[k];
            const unsigned u = *reinterpret_cast<const unsigned*>(src + (size_t)s * stride + lane * 2);
            union { unsigned u; float f; } lo{u << 16}, hi{u & 0xffff0000u};
            ax += lo.f;
            ay += hi.f;
        }
        const unsigned o = ((unsigned)f2bf(ay) << 16) | (unsigned)f2bf(ax * inv ? ax * inv : 0.f);
        // NOTE: compute carefully below instead (avoid the ?: trap)
        (void)o;
        const unsigned out = ((unsigned)f2bf(ay * inv) << 16) | (unsigned)f2bf(ax * inv);
        *reinterpret_cast<unsigned*>(dst + (size_t)node * stride + lane * 2) = out;
    }
}

// ---------------- MFMA GEMM: OUT = relu(A @ W^T + b), A [N][K2] bf16, W [128][K2] bf16 ----------------
// block = 256 threads = 4 waves; BM = 128 (wave -> 32 rows x 128 cols)
template <int K2>
__global__ __launch_bounds__(256) void mfma_gemm(const unsigned short* __restrict__ A,
                                                 const unsigned short* __restrict__ W,
                                                 const float* __restrict__ bias,
                                                 unsigned short* __restrict__ OUT, int o_stride,
                                                 int N) {
    const int tid = threadIdx.x;
    const int wid = tid >> 6;
    const int lane = tid & 63;
    const int m0 = blockIdx.x * 128;
    const int wm = m0 + wid * 32;
    const int lrow = lane & 15;
    const int kb = (lane >> 4) * 8;

    f32x4 acc[2][8];
#pragma unroll
    for (int i = 0; i < 2; ++i)
#pragma unroll
        for (int j = 0; j < 8; ++j) acc[i][j] = {0.f, 0.f, 0.f, 0.f};

    const int arow0 = wm + lrow;
    const int arow1 = wm + 16 + lrow;

#pragma unroll
    for (int k0 = 0; k0 < K2; k0 += 32) {
        short8 a0 = {0, 0, 0, 0, 0, 0, 0, 0}, a1 = a0;
        if (arow0 < N) a0 = *reinterpret_cast<const short8*>(A + (size_t)arow0 * K2 + k0 + kb);
        if (arow1 < N) a1 = *reinterpret_cast<const short8*>(A + (size_t)arow1 * K2 + k0 + kb);
        short8 b[8];
#pragma unroll
        for (int jb = 0; jb < 8; ++jb) {
            const int wrow = jb * 16 + lrow;
            b[jb] = *reinterpret_cast<const short8*>(W + (size_t)wrow * K2 + k0 + kb);
        }
#pragma unroll
        for (int jb = 0; jb < 8; ++jb) {
            acc[0][jb] = __builtin_amdgcn_mfma_f32_16x16x32_bf16(a0, b[jb], acc[0][jb], 0, 0, 0);
            acc[1][jb] = __builtin_amdgcn_mfma_f32_16x16x32_bf16(a1, b[jb], acc[1][jb], 0, 0, 0);
        }
    }

    float bias_r[8];
#pragma unroll
    for (int jb = 0; jb < 8; ++jb) bias_r[jb] = bias[jb * 16 + lrow];

    const int rbase = (lane >> 4) * 4;
#pragma unroll
    for (int i = 0; i < 2; ++i) {
#pragma unroll
        for (int r = 0; r < 4; ++r) {
            const int row = wm + i * 16 + rbase + r;
            if (row < N) {
                unsigned short* o = OUT + (size_t)row * o_stride + lrow;
#pragma unroll
                for (int jb = 0; jb < 8; ++jb) {
                    const float v = fmaxf(acc[i][jb][r] + bias_r[jb], 0.f);
                    o[jb * 16] = f2bf(v);
                }
            }
        }
    }
}

// ---------------- global mean pool + output head ----------------
__global__ __launch_bounds__(128) void pool_kernel(const unsigned short* __restrict__ H,
                                                   const int* __restrict__ batch,
                                                   const float* __restrict__ Wout,
                                                   const float* __restrict__ bout,
                                                   float* __restrict__ out, int N, int G) {
    const int g = blockIdx.x;
    const int t = threadIdx.x;
    int lo = 0, hi = N;
    while (lo < hi) {
        const int mid = (lo + hi) >> 1;
        if (batch[mid] < g) lo = mid + 1; else hi = mid;
    }
    const int start = lo;
    hi = N;
    while (lo < hi) {
        const int mid = (lo + hi) >> 1;
        if (batch[mid] < g + 1) lo = mid + 1; else hi = mid;
    }
    const int end = lo;
    float acc = 0.f;
    for (int n = start; n < end; ++n) acc += bf2f(H[(size_t)n * HID + t]);
    const float inv = 1.0f / fmaxf((float)(end - start), 1.0f);
    __shared__ float pl[HID];
    pl[t] = acc * inv;
    __syncthreads();
    if (t < TASKS) {
        float dot = bout[t];
        const float* w = Wout + t * HID;
        for (int k = 0; k < HID; ++k) dot = fmaf(pl[k], w[k], dot);
        out[(size_t)g * TASKS + t] = dot;
    }
}

// ---------------- launcher ----------------
extern "C" void kernel_launch(void* const* d_in, const int* in_sizes, int n_in,
                              void* d_out, int out_size, void* d_ws, size_t ws_size,
                              hipStream_t stream) {
    const float* x    = (const float*)d_in[0];
    const void*  e    = d_in[1];
    const void*  bt   = d_in[2];
    const float* Wl1  = (const float*)d_in[3];
    const float* bl1  = (const float*)d_in[4];
    const float* Wr1  = (const float*)d_in[5];
    const float* Wl2  = (const float*)d_in[6];
    const float* bl2  = (const float*)d_in[7];
    const float* Wr2  = (const float*)d_in[8];
    const float* Wl3  = (const float*)d_in[9];
    const float* bl3  = (const float*)d_in[10];
    const float* Wr3  = (const float*)d_in[11];
    const float* Wout = (const float*)d_in[12];
    const float* bout = (const float*)d_in[13];
    float* out = (float*)d_out;

    const int N = in_sizes[0] / 64;
    const int E = in_sizes[1] / 2;
    const int G = out_size / TASKS;

    char* base = (char*)d_ws;
    size_t off = 0;
    auto alloc = [&](size_t bytes) -> void* {
        void* p = base + off;
        off += (bytes + 255) & ~(size_t)255;
        return p;
    };
    int* flag    = (int*)alloc(256);
    int* src32   = (int*)alloc((size_t)E * 4);
    int* dst32   = (int*)alloc((size_t)E * 4);
    int* b32     = (int*)alloc((size_t)N * 4);
    int* deg     = (int*)alloc((size_t)N * 4);
    int* incl    = (int*)alloc((size_t)N * 4);
    int* bsums   = (int*)alloc(1024 * 4);
    int* rowptr  = (int*)alloc(((size_t)N + 1) * 4);
    int* fill    = (int*)alloc((size_t)N * 4);
    int* csr     = (int*)alloc((size_t)E * 4);
    unsigned short* wc1 = (unsigned short*)alloc((size_t)128 * 128 * 2);
    unsigned short* wc2 = (unsigned short*)alloc((size_t)128 * 256 * 2);
    unsigned short* wc3 = (unsigned short*)alloc((size_t)128 * 256 * 2);
    unsigned short* buf1 = (unsigned short*)alloc((size_t)N * 128 * 2);  // [x | agg1], later h3
    unsigned short* buf2 = (unsigned short*)alloc((size_t)N * 256 * 2);  // [h1 | agg2]
    unsigned short* buf3 = (unsigned short*)alloc((size_t)N * 256 * 2);  // [h2 | agg3]
    (void)ws_size;
    (void)n_in;

    hipMemsetAsync(deg, 0, (size_t)N * 4, stream);
    hipMemsetAsync(fill, 0, (size_t)N * 4, stream);

    detect_i64<<<1, 256, 0, stream>>>((const unsigned int*)e, flag);
    convert_edges<<<(E + 255) / 256, 256, 0, stream>>>(e, flag, src32, dst32, deg, E);
    convert_batch<<<(N + 255) / 256, 256, 0, stream>>>(bt, flag, b32, N);

    const int nsb = (N + 1023) / 1024;
    scan1<<<nsb, 256, 0, stream>>>(deg, incl, bsums, N);
    scan2<<<1, 256, 0, stream>>>(bsums, nsb);
    scan3<<<nsb, 256, 0, stream>>>(incl, bsums, rowptr, N);
    scatter_edges<<<(E + 255) / 256, 256, 0, stream>>>(src32, dst32, rowptr, fill, csr, E);

    cvt_x<<<(N * 16 + 255) / 256, 256, 0, stream>>>(x, buf1, N);
    cvt_w<<<(128 * 128 + 255) / 256, 256, 0, stream>>>(Wl1, Wr1, wc1, 64);
    cvt_w<<<(128 * 256 + 255) / 256, 256, 0, stream>>>(Wl2, Wr2, wc2, 128);
    cvt_w<<<(128 * 256 + 255) / 256, 256, 0, stream>>>(Wl3, Wr3, wc3, 128);

    const int aggBlocks = (int)(((size_t)N * 64 + 255) / 256);
    const int gemmBlocks = (N + 127) / 128;

    // layer 1
    agg_bf16<64><<<aggBlocks, 256, 0, stream>>>(buf1, buf1 + 64, 128, rowptr, csr, N);
    mfma_gemm<128><<<gemmBlocks, 256, 0, stream>>>(buf1, wc1, bl1, buf2, 256, N);
    // layer 2
    agg_bf16<128><<<aggBlocks, 256, 0, stream>>>(buf2, buf2 + 128, 256, rowptr, csr, N);
    mfma_gemm<256><<<gemmBlocks, 256, 0, stream>>>(buf2, wc2, bl2, buf3, 256, N);
    // layer 3
    agg_bf16<128><<<aggBlocks, 256, 0, stream>>>(buf3, buf3 + 128, 256, rowptr, csr, N);
    mfma_gemm<256><<<gemmBlocks, 256, 0, stream>>>(buf3, wc3, bl3, buf1, 128, N);

    pool_kernel<<<G, 128, 0, stream>>>(buf1, b32, Wout, bout, out, N, G);
}

// Round 3
// 556.758 us; speedup vs baseline: 1.5902x; 1.3406x over previous
//
#include <hip/hip_runtime.h>
#include <cstdint>
#include <cstddef>

static constexpr int HID = 128;
static constexpr int TASKS = 12;

using short8 = __attribute__((ext_vector_type(8))) short;  // 8 bf16 (4 VGPRs)
using f32x4  = __attribute__((ext_vector_type(4))) float;  // MFMA accumulator

__device__ inline unsigned short f2bf(float f) {
    union { float f; unsigned u; } v{f};
    unsigned r = v.u + 0x7fff + ((v.u >> 16) & 1);  // RNE
    return (unsigned short)(r >> 16);
}
__device__ inline float bf2f(unsigned short b) {
    union { unsigned u; float f; } v{(unsigned)b << 16};
    return v.f;
}

// ---------------- index dtype detection + conversion ----------------
__global__ void detect_i64(const unsigned int* __restrict__ ebuf, int* __restrict__ flag) {
    __shared__ unsigned int sh[256];
    const int t = threadIdx.x;
    unsigned int v = 0;
    for (int i = t; i < 1024; i += 256) v |= ebuf[2 * i + 1];
    sh[t] = v;
    __syncthreads();
    for (int s = 128; s > 0; s >>= 1) {
        if (t < s) sh[t] |= sh[t + s];
        __syncthreads();
    }
    if (t == 0) flag[0] = (sh[0] == 0u) ? 1 : 0;
}

__global__ void convert_edges(const void* __restrict__ ebuf, const int* __restrict__ flag,
                              int* __restrict__ src32, int* __restrict__ dst32,
                              int* __restrict__ deg, int E) {
    const int i = blockIdx.x * blockDim.x + threadIdx.x;
    if (i >= E) return;
    int s, d;
    if (*flag) {
        s = (int)((const long long*)ebuf)[i];
        d = (int)((const long long*)ebuf)[(size_t)E + i];
    } else {
        s = ((const int*)ebuf)[i];
        d = ((const int*)ebuf)[(size_t)E + i];
    }
    src32[i] = s;
    dst32[i] = d;
    atomicAdd(&deg[d], 1);
}

__global__ void convert_batch(const void* __restrict__ bbuf, const int* __restrict__ flag,
                              int* __restrict__ b32, int N) {
    const int i = blockIdx.x * blockDim.x + threadIdx.x;
    if (i >= N) return;
    b32[i] = (*flag) ? (int)((const long long*)bbuf)[i] : ((const int*)bbuf)[i];
}

// ---------------- exclusive scan (rowptr) ----------------
__global__ __launch_bounds__(256) void scan1(const int* __restrict__ deg, int* __restrict__ incl,
                                             int* __restrict__ bsums, int N) {
    __shared__ int sh[256];
    const int t = threadIdx.x;
    const int base = blockIdx.x * 1024 + t * 4;
    int v0 = (base + 0 < N) ? deg[base + 0] : 0;
    int v1 = (base + 1 < N) ? deg[base + 1] : 0;
    int v2 = (base + 2 < N) ? deg[base + 2] : 0;
    int v3 = (base + 3 < N) ? deg[base + 3] : 0;
    const int ts = v0 + v1 + v2 + v3;
    sh[t] = ts;
    __syncthreads();
    for (int off = 1; off < 256; off <<= 1) {
        int x = (t >= off) ? sh[t - off] : 0;
        __syncthreads();
        sh[t] += x;
        __syncthreads();
    }
    const int ex = sh[t] - ts;
    const int r0 = ex + v0, r1 = r0 + v1, r2 = r1 + v2, r3 = r2 + v3;
    if (base + 0 < N) incl[base + 0] = r0;
    if (base + 1 < N) incl[base + 1] = r1;
    if (base + 2 < N) incl[base + 2] = r2;
    if (base + 3 < N) incl[base + 3] = r3;
    if (t == 255) bsums[blockIdx.x] = sh[255];
}

__global__ __launch_bounds__(256) void scan2(int* __restrict__ bsums, int nb) {
    __shared__ int sh[256];
    const int t = threadIdx.x;
    const int v = (t < nb) ? bsums[t] : 0;
    sh[t] = v;
    __syncthreads();
    for (int off = 1; off < 256; off <<= 1) {
        int x = (t >= off) ? sh[t - off] : 0;
        __syncthreads();
        sh[t] += x;
        __syncthreads();
    }
    if (t < nb) bsums[t] = sh[t] - v;  // exclusive
}

// writes rowptr AND initializes fill[] = rowptr[] (next-free-slot array)
__global__ __launch_bounds__(256) void scan3(const int* __restrict__ incl, const int* __restrict__ bsums,
                                             int* __restrict__ rowptr, int* __restrict__ fill, int N) {
    const int t = threadIdx.x;
    const int base = blockIdx.x * 1024 + t * 4;
    const int off = bsums[blockIdx.x];
#pragma unroll
    for (int j = 0; j < 4; ++j) {
        if (base + j < N) {
            const int v = incl[base + j] + off;
            rowptr[base + j + 1] = v;
            if (base + j + 1 < N) fill[base + j + 1] = v;
        }
    }
    if (blockIdx.x == 0 && t == 0) { rowptr[0] = 0; fill[0] = 0; }
}

__global__ void scatter_edges(const int* __restrict__ src32, const int* __restrict__ dst32,
                              int* __restrict__ fill, int* __restrict__ csr, int E) {
    const int i = blockIdx.x * blockDim.x + threadIdx.x;
    if (i >= E) return;
    const int pos = atomicAdd(&fill[dst32[i]], 1);
    csr[pos] = src32[i];
}

// ---------------- dtype conversions ----------------
__global__ void cvt_x(const float* __restrict__ x, unsigned short* __restrict__ buf1, int N) {
    const int idx = blockIdx.x * blockDim.x + threadIdx.x;
    if (idx >= N * 16) return;
    const int n = idx >> 4;
    const int k4 = (idx & 15) * 4;
    const float4 v = *reinterpret_cast<const float4*>(x + (size_t)n * 64 + k4);
    ushort4 o;
    o.x = f2bf(v.x); o.y = f2bf(v.y); o.z = f2bf(v.z); o.w = f2bf(v.w);
    *reinterpret_cast<ushort4*>(buf1 + (size_t)n * 128 + k4) = o;
}

__global__ void cvt_w(const float* __restrict__ Wl, const float* __restrict__ Wr,
                      unsigned short* __restrict__ out, int KH) {
    const int idx = blockIdx.x * blockDim.x + threadIdx.x;
    const int K2 = 2 * KH;
    if (idx >= 128 * K2) return;
    const int j = idx / K2;
    const int k = idx % K2;
    const float v = (k < KH) ? Wl[(size_t)j * KH + k] : Wr[(size_t)j * KH + k - KH];
    out[idx] = f2bf(v);
}

// ---------------- mean aggregation (bf16), high-MLP ----------------
// One wave per node. Each lane loads 16B (8 bf16) per iteration:
//   D=128: 16 lanes/row, 4 rows/iter;  D=64: 8 lanes/row, 8 rows/iter.
// Cross-group shfl_xor reduce at the end; low lanes store one short8.
template <int D>
__global__ __launch_bounds__(256) void agg_bf16(const unsigned short* __restrict__ src,
                                                unsigned short* __restrict__ dst, int stride,
                                                const int* __restrict__ rowptr,
                                                const int* __restrict__ csr, int N) {
    constexpr int LPR = D * 2 / 16;       // lanes per row (16B each): 16 for D=128, 8 for D=64
    constexpr int RPI = 64 / LPR;         // rows per iteration: 4 or 8
    const int gid = blockIdx.x * blockDim.x + threadIdx.x;
    const int node = gid >> 6;
    const int lane = gid & 63;
    if (node >= N) return;
    const int beg = rowptr[node];
    const int end = rowptr[node + 1];
    const int g = lane / LPR;             // row group within wave
    const int m = lane % LPR;             // 16B chunk within row

    float acc[8] = {0.f, 0.f, 0.f, 0.f, 0.f, 0.f, 0.f, 0.f};

    for (int k = beg + g; k < end; k += RPI) {
        const int s = csr[k];
        const short8 v = *reinterpret_cast<const short8*>(src + (size_t)s * stride + m * 8);
        const unsigned* u = reinterpret_cast<const unsigned*>(&v);
#pragma unroll
        for (int j = 0; j < 4; ++j) {
            union { unsigned u; float f; } lo{u[j] << 16}, hi{u[j] & 0xffff0000u};
            acc[2 * j]     += lo.f;
            acc[2 * j + 1] += hi.f;
        }
    }

    // reduce across row-groups (high lane bits)
#pragma unroll
    for (int mask = LPR; mask < 64; mask <<= 1) {
#pragma unroll
        for (int j = 0; j < 8; ++j) acc[j] += __shfl_xor(acc[j], mask);
    }

    if (lane < LPR) {
        const float inv = 1.0f / fmaxf((float)(end - beg), 1.0f);
        unsigned o[4];
#pragma unroll
        for (int j = 0; j < 4; ++j) {
            o[j] = ((unsigned)f2bf(acc[2 * j + 1] * inv) << 16) | (unsigned)f2bf(acc[2 * j] * inv);
        }
        *reinterpret_cast<uint4*>(dst + (size_t)node * stride + m * 8) =
            make_uint4(o[0], o[1], o[2], o[3]);
    }
}

// ---------------- MFMA GEMM: OUT = relu(A @ W^T + b) ----------------
template <int K2>
__global__ __launch_bounds__(256) void mfma_gemm(const unsigned short* __restrict__ A,
                                                 const unsigned short* __restrict__ W,
                                                 const float* __restrict__ bias,
                                                 unsigned short* __restrict__ OUT, int o_stride,
                                                 int N) {
    const int tid = threadIdx.x;
    const int wid = tid >> 6;
    const int lane = tid & 63;
    const int m0 = blockIdx.x * 128;
    const int wm = m0 + wid * 32;
    const int lrow = lane & 15;
    const int kb = (lane >> 4) * 8;

    f32x4 acc[2][8];
#pragma unroll
    for (int i = 0; i < 2; ++i)
#pragma unroll
        for (int j = 0; j < 8; ++j) acc[i][j] = {0.f, 0.f, 0.f, 0.f};

    const int arow0 = wm + lrow;
    const int arow1 = wm + 16 + lrow;

#pragma unroll
    for (int k0 = 0; k0 < K2; k0 += 32) {
        short8 a0 = {0, 0, 0, 0, 0, 0, 0, 0}, a1 = a0;
        if (arow0 < N) a0 = *reinterpret_cast<const short8*>(A + (size_t)arow0 * K2 + k0 + kb);
        if (arow1 < N) a1 = *reinterpret_cast<const short8*>(A + (size_t)arow1 * K2 + k0 + kb);
        short8 b[8];
#pragma unroll
        for (int jb = 0; jb < 8; ++jb) {
            const int wrow = jb * 16 + lrow;
            b[jb] = *reinterpret_cast<const short8*>(W + (size_t)wrow * K2 + k0 + kb);
        }
#pragma unroll
        for (int jb = 0; jb < 8; ++jb) {
            acc[0][jb] = __builtin_amdgcn_mfma_f32_16x16x32_bf16(a0, b[jb], acc[0][jb], 0, 0, 0);
            acc[1][jb] = __builtin_amdgcn_mfma_f32_16x16x32_bf16(a1, b[jb], acc[1][jb], 0, 0, 0);
        }
    }

    float bias_r[8];
#pragma unroll
    for (int jb = 0; jb < 8; ++jb) bias_r[jb] = bias[jb * 16 + lrow];

    const int rbase = (lane >> 4) * 4;
#pragma unroll
    for (int i = 0; i < 2; ++i) {
#pragma unroll
        for (int r = 0; r < 4; ++r) {
            const int row = wm + i * 16 + rbase + r;
            if (row < N) {
                unsigned short* o = OUT + (size_t)row * o_stride + lrow;
#pragma unroll
                for (int jb = 0; jb < 8; ++jb) {
                    const float v = fmaxf(acc[i][jb][r] + bias_r[jb], 0.f);
                    o[jb * 16] = f2bf(v);
                }
            }
        }
    }
}

// ---------------- global mean pool + output head ----------------
__global__ __launch_bounds__(128) void pool_kernel(const unsigned short* __restrict__ H,
                                                   const int* __restrict__ batch,
                                                   const float* __restrict__ Wout,
                                                   const float* __restrict__ bout,
                                                   float* __restrict__ out, int N, int G) {
    const int g = blockIdx.x;
    const int t = threadIdx.x;
    int lo = 0, hi = N;
    while (lo < hi) {
        const int mid = (lo + hi) >> 1;
        if (batch[mid] < g) lo = mid + 1; else hi = mid;
    }
    const int start = lo;
    hi = N;
    while (lo < hi) {
        const int mid = (lo + hi) >> 1;
        if (batch[mid] < g + 1) lo = mid + 1; else hi = mid;
    }
    const int end = lo;
    float acc = 0.f;
    for (int n = start; n < end; ++n) acc += bf2f(H[(size_t)n * HID + t]);
    const float inv = 1.0f / fmaxf((float)(end - start), 1.0f);
    __shared__ float pl[HID];
    pl[t] = acc * inv;
    __syncthreads();
    if (t < TASKS) {
        float dot = bout[t];
        const float* w = Wout + t * HID;
        for (int k = 0; k < HID; ++k) dot = fmaf(pl[k], w[k], dot);
        out[(size_t)g * TASKS + t] = dot;
    }
}

// ---------------- launcher ----------------
extern "C" void kernel_launch(void* const* d_in, const int* in_sizes, int n_in,
                              void* d_out, int out_size, void* d_ws, size_t ws_size,
                              hipStream_t stream) {
    const float* x    = (const float*)d_in[0];
    const void*  e    = d_in[1];
    const void*  bt   = d_in[2];
    const float* Wl1  = (const float*)d_in[3];
    const float* bl1  = (const float*)d_in[4];
    const float* Wr1  = (const float*)d_in[5];
    const float* Wl2  = (const float*)d_in[6];
    const float* bl2  = (const float*)d_in[7];
    const float* Wr2  = (const float*)d_in[8];
    const float* Wl3  = (const float*)d_in[9];
    const float* bl3  = (const float*)d_in[10];
    const float* Wr3  = (const float*)d_in[11];
    const float* Wout = (const float*)d_in[12];
    const float* bout = (const float*)d_in[13];
    float* out = (float*)d_out;

    const int N = in_sizes[0] / 64;
    const int E = in_sizes[1] / 2;
    const int G = out_size / TASKS;

    char* base = (char*)d_ws;
    size_t off = 0;
    auto alloc = [&](size_t bytes) -> void* {
        void* p = base + off;
        off += (bytes + 255) & ~(size_t)255;
        return p;
    };
    int* flag    = (int*)alloc(256);
    int* src32   = (int*)alloc((size_t)E * 4);
    int* dst32   = (int*)alloc((size_t)E * 4);
    int* b32     = (int*)alloc((size_t)N * 4);
    int* deg     = (int*)alloc((size_t)N * 4);
    int* incl    = (int*)alloc((size_t)N * 4);
    int* bsums   = (int*)alloc(1024 * 4);
    int* rowptr  = (int*)alloc(((size_t)N + 1) * 4);
    int* fill    = (int*)alloc((size_t)N * 4);
    int* csr     = (int*)alloc((size_t)E * 4);
    unsigned short* wc1 = (unsigned short*)alloc((size_t)128 * 128 * 2);
    unsigned short* wc2 = (unsigned short*)alloc((size_t)128 * 256 * 2);
    unsigned short* wc3 = (unsigned short*)alloc((size_t)128 * 256 * 2);
    unsigned short* buf1 = (unsigned short*)alloc((size_t)N * 128 * 2);  // [x | agg1], later h3
    unsigned short* buf2 = (unsigned short*)alloc((size_t)N * 256 * 2);  // [h1 | agg2]
    unsigned short* buf3 = (unsigned short*)alloc((size_t)N * 256 * 2);  // [h2 | agg3]
    (void)ws_size;
    (void)n_in;

    hipMemsetAsync(deg, 0, (size_t)N * 4, stream);

    detect_i64<<<1, 256, 0, stream>>>((const unsigned int*)e, flag);
    convert_edges<<<(E + 255) / 256, 256, 0, stream>>>(e, flag, src32, dst32, deg, E);
    convert_batch<<<(N + 255) / 256, 256, 0, stream>>>(bt, flag, b32, N);

    const int nsb = (N + 1023) / 1024;
    scan1<<<nsb, 256, 0, stream>>>(deg, incl, bsums, N);
    scan2<<<1, 256, 0, stream>>>(bsums, nsb);
    scan3<<<nsb, 256, 0, stream>>>(incl, bsums, rowptr, fill, N);
    scatter_edges<<<(E + 255) / 256, 256, 0, stream>>>(src32, dst32, fill, csr, E);

    cvt_x<<<(N * 16 + 255) / 256, 256, 0, stream>>>(x, buf1, N);
    cvt_w<<<(128 * 128 + 255) / 256, 256, 0, stream>>>(Wl1, Wr1, wc1, 64);
    cvt_w<<<(128 * 256 + 255) / 256, 256, 0, stream>>>(Wl2, Wr2, wc2, 128);
    cvt_w<<<(128 * 256 + 255) / 256, 256, 0, stream>>>(Wl3, Wr3, wc3, 128);

    const int aggBlocks = (int)(((size_t)N * 64 + 255) / 256);
    const int gemmBlocks = (N + 127) / 128;

    // layer 1
    agg_bf16<64><<<aggBlocks, 256, 0, stream>>>(buf1, buf1 + 64, 128, rowptr, csr, N);
    mfma_gemm<128><<<gemmBlocks, 256, 0, stream>>>(buf1, wc1, bl1, buf2, 256, N);
    // layer 2
    agg_bf16<128><<<aggBlocks, 256, 0, stream>>>(buf2, buf2 + 128, 256, rowptr, csr, N);
    mfma_gemm<256><<<gemmBlocks, 256, 0, stream>>>(buf2, wc2, bl2, buf3, 256, N);
    // layer 3
    agg_bf16<128><<<aggBlocks, 256, 0, stream>>>(buf3, buf3 + 128, 256, rowptr, csr, N);
    mfma_gemm<256><<<gemmBlocks, 256, 0, stream>>>(buf3, wc3, bl3, buf1, 128, N);

    pool_kernel<<<G, 128, 0, stream>>>(buf1, b32, Wout, bout, out, N, G);
}

// Round 9
// 446.450 us; speedup vs baseline: 1.9831x; 1.2471x over previous
//
#include <hip/hip_runtime.h>
#include <cstdint>
#include <cstddef>

static constexpr int HID = 128;
static constexpr int TASKS = 12;

using short8 = __attribute__((ext_vector_type(8))) short;  // 8 bf16 (4 VGPRs)
using f32x4  = __attribute__((ext_vector_type(4))) float;  // MFMA accumulator

__device__ inline unsigned short f2bf(float f) {
    union { float f; unsigned u; } v{f};
    unsigned r = v.u + 0x7fff + ((v.u >> 16) & 1);  // RNE
    return (unsigned short)(r >> 16);
}
__device__ inline float bf2f(unsigned short b) {
    union { unsigned u; float f; } v{(unsigned)b << 16};
    return v.f;
}

// ---------------- index dtype detection ----------------
__global__ void detect_i64(const unsigned int* __restrict__ ebuf, int* __restrict__ flag) {
    __shared__ unsigned int sh[256];
    const int t = threadIdx.x;
    unsigned int v = 0;
    for (int i = t; i < 1024; i += 256) v |= ebuf[2 * i + 1];
    sh[t] = v;
    __syncthreads();
    for (int s = 128; s > 0; s >>= 1) {
        if (t < s) sh[t] |= sh[t + s];
        __syncthreads();
    }
    if (t == 0) flag[0] = (sh[0] == 0u) ? 1 : 0;
}

__global__ void convert_batch(const void* __restrict__ bbuf, const int* __restrict__ flag,
                              int* __restrict__ b32, int N) {
    const int i = blockIdx.x * blockDim.x + threadIdx.x;
    if (i >= N) return;
    b32[i] = (*flag) ? (int)((const long long*)bbuf)[i] : ((const int*)bbuf)[i];
}

// ---------------- CSR build, phase 1: LDS-binned edge partition ----------------
// Buckets of 256 consecutive dst nodes (bucket = dst>>8; requires N <= 131072).
// Each block bins EPB edges in LDS, reserves per-bucket space with ONE global
// atomic per (block,bucket), then writes pairs out coalesced per bucket segment.
__global__ __launch_bounds__(256) void bin_convert(const void* __restrict__ ebuf,
                                                   const int* __restrict__ flag,
                                                   uint2* __restrict__ pairs,
                                                   int* __restrict__ bucket_fill,
                                                   int E, int CAP) {
    constexpr int EPB = 4096, EPT = 16;
    __shared__ int cnt[512];
    __shared__ int base_[512];
    __shared__ int gb[512];
    __shared__ int s2[256];
    __shared__ uint2 lp[EPB];
    const int t = threadIdx.x;
    const int start = blockIdx.x * EPB;
    const int nE = min(EPB, E - start);
    cnt[t] = 0;
    cnt[t + 256] = 0;
    __syncthreads();

    unsigned ss[EPT], dd[EPT];
    unsigned short loc[EPT];
    const bool is64 = (*flag != 0);
#pragma unroll
    for (int j = 0; j < EPT; ++j) {
        const int i = start + t + j * 256;
        if (i - start < nE) {
            if (is64) {
                ss[j] = (unsigned)((const long long*)ebuf)[i];
                dd[j] = (unsigned)((const long long*)ebuf)[(size_t)E + i];
            } else {
                ss[j] = ((const unsigned*)ebuf)[i];
                dd[j] = ((const unsigned*)ebuf)[(size_t)E + i];
            }
            loc[j] = (unsigned short)atomicAdd(&cnt[dd[j] >> 8], 1);
        }
    }
    __syncthreads();
    // exclusive scan of 512 bucket counts by 256 threads (2 per thread)
    const int a = cnt[2 * t], b_ = cnt[2 * t + 1];
    s2[t] = a + b_;
    __syncthreads();
    for (int off = 1; off < 256; off <<= 1) {
        const int x = (t >= off) ? s2[t - off] : 0;
        __syncthreads();
        s2[t] += x;
        __syncthreads();
    }
    const int ex = s2[t] - a - b_;
    base_[2 * t] = ex;
    base_[2 * t + 1] = ex + a;
    __syncthreads();
    // reorder into LDS, bucket-grouped
#pragma unroll
    for (int j = 0; j < EPT; ++j) {
        const int i = start + t + j * 256;
        if (i - start < nE) {
            const int b = dd[j] >> 8;
            lp[base_[b] + loc[j]] = make_uint2(ss[j], dd[j]);
        }
    }
    // reserve global segment space: one atomic per non-empty bucket
    for (int b = t; b < 512; b += 256) {
        const int c = cnt[b];
        gb[b] = c ? atomicAdd(&bucket_fill[b], c) : 0;
    }
    __syncthreads();
    // coalesced copy-out into per-bucket global segments
    for (int i = t; i < nE; i += 256) {
        const uint2 p = lp[i];
        const int b = (int)(p.y >> 8);
        pairs[(size_t)b * CAP + gb[b] + (i - base_[b])] = p;
    }
}

// ---------------- CSR build, phase 2: per-bucket scatter (L2-local) ----------------
// One block per bucket: histogram its 256-node window, LDS scan -> rowbeg/deg
// (no global scan needed), then scatter src ids within the bucket's private
// csr window. All writes for a window come from one block -> no cross-XCD
// write amplification.
__global__ __launch_bounds__(256) void bucket_scatter(const uint2* __restrict__ pairs,
                                                      const int* __restrict__ bucket_fill,
                                                      int* __restrict__ rowbeg,
                                                      int* __restrict__ degO,
                                                      unsigned* __restrict__ csrb,
                                                      int N, int CAP) {
    const int b = blockIdx.x;
    const int t = threadIdx.x;
    const int d0 = b << 8;
    const int cnt = bucket_fill[b];
    const size_t seg = (size_t)b * CAP;
    __shared__ int degw[256];
    __shared__ int offw[256];
    __shared__ int frw[256];
    degw[t] = 0;
    __syncthreads();
    for (int i = t; i < cnt; i += 256) {
        const uint2 p = pairs[seg + i];
        atomicAdd(&degw[p.y & 255], 1);
    }
    __syncthreads();
    const int v = degw[t];
    offw[t] = v;
    __syncthreads();
    for (int off = 1; off < 256; off <<= 1) {
        const int x = (t >= off) ? offw[t - off] : 0;
        __syncthreads();
        offw[t] += x;
        __syncthreads();
    }
    const int ex = offw[t] - v;
    const int node = d0 + t;
    if (node < N) {
        rowbeg[node] = (int)(seg + ex);
        degO[node] = v;
    }
    frw[t] = ex;
    __syncthreads();
    for (int i = t; i < cnt; i += 256) {
        const uint2 p = pairs[seg + i];
        const int pos = atomicAdd(&frw[p.y & 255], 1);
        csrb[seg + pos] = p.x;
    }
}

// ---------------- dtype conversions ----------------
__global__ void cvt_x(const float* __restrict__ x, unsigned short* __restrict__ buf1, int N) {
    const int idx = blockIdx.x * blockDim.x + threadIdx.x;
    if (idx >= N * 16) return;
    const int n = idx >> 4;
    const int k4 = (idx & 15) * 4;
    const float4 v = *reinterpret_cast<const float4*>(x + (size_t)n * 64 + k4);
    ushort4 o;
    o.x = f2bf(v.x); o.y = f2bf(v.y); o.z = f2bf(v.z); o.w = f2bf(v.w);
    *reinterpret_cast<ushort4*>(buf1 + (size_t)n * 128 + k4) = o;
}

__global__ void cvt_w(const float* __restrict__ Wl, const float* __restrict__ Wr,
                      unsigned short* __restrict__ out, int KH) {
    const int idx = blockIdx.x * blockDim.x + threadIdx.x;
    const int K2 = 2 * KH;
    if (idx >= 128 * K2) return;
    const int j = idx / K2;
    const int k = idx % K2;
    const float v = (k < KH) ? Wl[(size_t)j * KH + k] : Wr[(size_t)j * KH + k - KH];
    out[idx] = f2bf(v);
}

// ---------------- mean aggregation (bf16), high-MLP ----------------
template <int D>
__global__ __launch_bounds__(256) void agg_bf16(const unsigned short* __restrict__ src,
                                                unsigned short* __restrict__ dst, int stride,
                                                const int* __restrict__ rowbeg,
                                                const int* __restrict__ degO,
                                                const unsigned* __restrict__ csrb, int N) {
    constexpr int LPR = D * 2 / 16;       // lanes per row (16B each): 16 for D=128, 8 for D=64
    constexpr int RPI = 64 / LPR;         // rows per iteration: 4 or 8
    const int gid = blockIdx.x * blockDim.x + threadIdx.x;
    const int node = gid >> 6;
    const int lane = gid & 63;
    if (node >= N) return;
    const int beg = rowbeg[node];
    const int dg = degO[node];
    const int end = beg + dg;
    const int g = lane / LPR;
    const int m = lane % LPR;

    float acc[8] = {0.f, 0.f, 0.f, 0.f, 0.f, 0.f, 0.f, 0.f};

    for (int k = beg + g; k < end; k += RPI) {
        const int s = (int)csrb[k];
        const short8 v = *reinterpret_cast<const short8*>(src + (size_t)s * stride + m * 8);
        const unsigned* u = reinterpret_cast<const unsigned*>(&v);
#pragma unroll
        for (int j = 0; j < 4; ++j) {
            union { unsigned u; float f; } lo{u[j] << 16}, hi{u[j] & 0xffff0000u};
            acc[2 * j]     += lo.f;
            acc[2 * j + 1] += hi.f;
        }
    }

#pragma unroll
    for (int mask = LPR; mask < 64; mask <<= 1) {
#pragma unroll
        for (int j = 0; j < 8; ++j) acc[j] += __shfl_xor(acc[j], mask);
    }

    if (lane < LPR) {
        const float inv = 1.0f / fmaxf((float)dg, 1.0f);
        unsigned o[4];
#pragma unroll
        for (int j = 0; j < 4; ++j) {
            o[j] = ((unsigned)f2bf(acc[2 * j + 1] * inv) << 16) | (unsigned)f2bf(acc[2 * j] * inv);
        }
        *reinterpret_cast<uint4*>(dst + (size_t)node * stride + m * 8) =
            make_uint4(o[0], o[1], o[2], o[3]);
    }
}

// ---------------- MFMA GEMM: OUT = relu(A @ W^T + b) ----------------
template <int K2>
__global__ __launch_bounds__(256) void mfma_gemm(const unsigned short* __restrict__ A,
                                                 const unsigned short* __restrict__ W,
                                                 const float* __restrict__ bias,
                                                 unsigned short* __restrict__ OUT, int o_stride,
                                                 int N) {
    const int tid = threadIdx.x;
    const int wid = tid >> 6;
    const int lane = tid & 63;
    const int m0 = blockIdx.x * 128;
    const int wm = m0 + wid * 32;
    const int lrow = lane & 15;
    const int kb = (lane >> 4) * 8;

    f32x4 acc[2][8];
#pragma unroll
    for (int i = 0; i < 2; ++i)
#pragma unroll
        for (int j = 0; j < 8; ++j) acc[i][j] = {0.f, 0.f, 0.f, 0.f};

    const int arow0 = wm + lrow;
    const int arow1 = wm + 16 + lrow;

#pragma unroll
    for (int k0 = 0; k0 < K2; k0 += 32) {
        short8 a0 = {0, 0, 0, 0, 0, 0, 0, 0}, a1 = a0;
        if (arow0 < N) a0 = *reinterpret_cast<const short8*>(A + (size_t)arow0 * K2 + k0 + kb);
        if (arow1 < N) a1 = *reinterpret_cast<const short8*>(A + (size_t)arow1 * K2 + k0 + kb);
        short8 b[8];
#pragma unroll
        for (int jb = 0; jb < 8; ++jb) {
            const int wrow = jb * 16 + lrow;
            b[jb] = *reinterpret_cast<const short8*>(W + (size_t)wrow * K2 + k0 + kb);
        }
#pragma unroll
        for (int jb = 0; jb < 8; ++jb) {
            acc[0][jb] = __builtin_amdgcn_mfma_f32_16x16x32_bf16(a0, b[jb], acc[0][jb], 0, 0, 0);
            acc[1][jb] = __builtin_amdgcn_mfma_f32_16x16x32_bf16(a1, b[jb], acc[1][jb], 0, 0, 0);
        }
    }

    float bias_r[8];
#pragma unroll
    for (int jb = 0; jb < 8; ++jb) bias_r[jb] = bias[jb * 16 + lrow];

    const int rbase = (lane >> 4) * 4;
#pragma unroll
    for (int i = 0; i < 2; ++i) {
#pragma unroll
        for (int r = 0; r < 4; ++r) {
            const int row = wm + i * 16 + rbase + r;
            if (row < N) {
                unsigned short* o = OUT + (size_t)row * o_stride + lrow;
#pragma unroll
                for (int jb = 0; jb < 8; ++jb) {
                    const float v = fmaxf(acc[i][jb][r] + bias_r[jb], 0.f);
                    o[jb * 16] = f2bf(v);
                }
            }
        }
    }
}

// ---------------- global mean pool + output head ----------------
__global__ __launch_bounds__(128) void pool_kernel(const unsigned short* __restrict__ H,
                                                   const int* __restrict__ batch,
                                                   const float* __restrict__ Wout,
                                                   const float* __restrict__ bout,
                                                   float* __restrict__ out, int N, int G) {
    const int g = blockIdx.x;
    const int t = threadIdx.x;
    int lo = 0, hi = N;
    while (lo < hi) {
        const int mid = (lo + hi) >> 1;
        if (batch[mid] < g) lo = mid + 1; else hi = mid;
    }
    const int start = lo;
    hi = N;
    while (lo < hi) {
        const int mid = (lo + hi) >> 1;
        if (batch[mid] < g + 1) lo = mid + 1; else hi = mid;
    }
    const int end = lo;
    float acc = 0.f;
    for (int n = start; n < end; ++n) acc += bf2f(H[(size_t)n * HID + t]);
    const float inv = 1.0f / fmaxf((float)(end - start), 1.0f);
    __shared__ float pl[HID];
    pl[t] = acc * inv;
    __syncthreads();
    if (t < TASKS) {
        float dot = bout[t];
        const float* w = Wout + t * HID;
        for (int k = 0; k < HID; ++k) dot = fmaf(pl[k], w[k], dot);
        out[(size_t)g * TASKS + t] = dot;
    }
}

// ---------------- launcher ----------------
extern "C" void kernel_launch(void* const* d_in, const int* in_sizes, int n_in,
                              void* d_out, int out_size, void* d_ws, size_t ws_size,
                              hipStream_t stream) {
    const float* x    = (const float*)d_in[0];
    const void*  e    = d_in[1];
    const void*  bt   = d_in[2];
    const float* Wl1  = (const float*)d_in[3];
    const float* bl1  = (const float*)d_in[4];
    const float* Wr1  = (const float*)d_in[5];
    const float* Wl2  = (const float*)d_in[6];
    const float* bl2  = (const float*)d_in[7];
    const float* Wr2  = (const float*)d_in[8];
    const float* Wl3  = (const float*)d_in[9];
    const float* bl3  = (const float*)d_in[10];
    const float* Wr3  = (const float*)d_in[11];
    const float* Wout = (const float*)d_in[12];
    const float* bout = (const float*)d_in[13];
    float* out = (float*)d_out;

    const int N = in_sizes[0] / 64;   // requires N <= 131072 (bucket = dst>>8, <=512 buckets)
    const int E = in_sizes[1] / 2;
    const int G = out_size / TASKS;
    const int NB = (N + 255) >> 8;
    const int CAP = 6144;             // per-bucket capacity; mean ~3200 for this input, +52 sigma

    char* base = (char*)d_ws;
    size_t off = 0;
    auto alloc = [&](size_t bytes) -> void* {
        void* p = base + off;
        off += (bytes + 255) & ~(size_t)255;
        return p;
    };
    int* flag        = (int*)alloc(256);
    int* b32         = (int*)alloc((size_t)N * 4);
    int* bucket_fill = (int*)alloc((size_t)NB * 4);
    int* rowbeg      = (int*)alloc((size_t)N * 4);
    int* degO        = (int*)alloc((size_t)N * 4);
    uint2* pairs     = (uint2*)alloc((size_t)NB * CAP * 8);
    unsigned* csrb   = (unsigned*)alloc((size_t)NB * CAP * 4);
    unsigned short* wc1 = (unsigned short*)alloc((size_t)128 * 128 * 2);
    unsigned short* wc2 = (unsigned short*)alloc((size_t)128 * 256 * 2);
    unsigned short* wc3 = (unsigned short*)alloc((size_t)128 * 256 * 2);
    unsigned short* buf1 = (unsigned short*)alloc((size_t)N * 128 * 2);  // [x | agg1], later h3
    unsigned short* buf2 = (unsigned short*)alloc((size_t)N * 256 * 2);  // [h1 | agg2]
    unsigned short* buf3 = (unsigned short*)alloc((size_t)N * 256 * 2);  // [h2 | agg3]
    (void)ws_size;
    (void)n_in;

    hipMemsetAsync(bucket_fill, 0, (size_t)NB * 4, stream);

    detect_i64<<<1, 256, 0, stream>>>((const unsigned int*)e, flag);
    convert_batch<<<(N + 255) / 256, 256, 0, stream>>>(bt, flag, b32, N);
    bin_convert<<<(E + 4095) / 4096, 256, 0, stream>>>(e, flag, pairs, bucket_fill, E, CAP);
    bucket_scatter<<<NB, 256, 0, stream>>>(pairs, bucket_fill, rowbeg, degO, csrb, N, CAP);

    cvt_x<<<(N * 16 + 255) / 256, 256, 0, stream>>>(x, buf1, N);
    cvt_w<<<(128 * 128 + 255) / 256, 256, 0, stream>>>(Wl1, Wr1, wc1, 64);
    cvt_w<<<(128 * 256 + 255) / 256, 256, 0, stream>>>(Wl2, Wr2, wc2, 128);
    cvt_w<<<(128 * 256 + 255) / 256, 256, 0, stream>>>(Wl3, Wr3, wc3, 128);

    const int aggBlocks = (int)(((size_t)N * 64 + 255) / 256);
    const int gemmBlocks = (N + 127) / 128;

    // layer 1
    agg_bf16<64><<<aggBlocks, 256, 0, stream>>>(buf1, buf1 + 64, 128, rowbeg, degO, csrb, N);
    mfma_gemm<128><<<gemmBlocks, 256, 0, stream>>>(buf1, wc1, bl1, buf2, 256, N);
    // layer 2
    agg_bf16<128><<<aggBlocks, 256, 0, stream>>>(buf2, buf2 + 128, 256, rowbeg, degO, csrb, N);
    mfma_gemm<256><<<gemmBlocks, 256, 0, stream>>>(buf2, wc2, bl2, buf3, 256, N);
    // layer 3
    agg_bf16<128><<<aggBlocks, 256, 0, stream>>>(buf3, buf3 + 128, 256, rowbeg, degO, csrb, N);
    mfma_gemm<256><<<gemmBlocks, 256, 0, stream>>>(buf3, wc3, bl3, buf1, 128, N);

    pool_kernel<<<G, 128, 0, stream>>>(buf1, b32, Wout, bout, out, N, G);
}